// Round 9
// baseline (1097.502 us; speedup 1.0000x reference)
//
#include <hip/hip_runtime.h>
#include <hip/hip_bf16.h>

typedef __attribute__((ext_vector_type(4))) float f32x4;
typedef __attribute__((ext_vector_type(8))) short s16x8;
typedef __attribute__((ext_vector_type(4))) int int4v;

#define DEVI __device__ __forceinline__

constexpr int NN = 50000;
constexpr int NE = 200000;
constexpr float BN_EPS = 1e-5f;

DEVI float bfbits2f(unsigned v) { union { unsigned u; float f; } t; t.u = v << 16; return t.f; }
DEVI float lrelu_f(float v) { return v >= 0.f ? v : 0.01f * v; }

// ---------------- prep: W2T[n][k] = bf16(W2[k][n]) for both layers ----------------
__global__ void k_transpose_w2(const float* __restrict__ A0, const float* __restrict__ A1,
                               __hip_bfloat16* __restrict__ T0, __hip_bfloat16* __restrict__ T1) {
  const float* W2 = blockIdx.y ? A1 : A0;
  __hip_bfloat16* W2T = blockIdx.y ? T1 : T0;
  __shared__ float tile[32][33];
  int bx = blockIdx.x % 16, by = blockIdx.x / 16;
  int t = threadIdx.x;
  int r = t / 32, c = t % 32;
  for (int rr = r; rr < 32; rr += 8)
    tile[rr][c] = W2[(size_t)(by * 32 + rr) * 512 + bx * 32 + c];
  __syncthreads();
  for (int rr = r; rr < 32; rr += 8)
    W2T[(size_t)(bx * 32 + rr) * 512 + by * 32 + c] = __float2bfloat16(tile[c][rr]);
}

// W1T[n][k] = bf16(W1[k][n]); W1 is [8][512]
__global__ void k_transpose_w1(const float* __restrict__ A0, const float* __restrict__ A1,
                               __hip_bfloat16* __restrict__ T0, __hip_bfloat16* __restrict__ T1) {
  const float* W1 = blockIdx.y ? A1 : A0;
  __hip_bfloat16* W1T = blockIdx.y ? T1 : T0;
  int tid = blockIdx.x * 256 + threadIdx.x;
  if (tid < 8 * 512) {
    int k = tid / 512, n = tid % 512;
    W1T[n * 8 + k] = __float2bfloat16(W1[tid]);
  }
}

// ---------------- counting sort by dst -> perm ----------------
__global__ void k_count(const int* __restrict__ dst, int* __restrict__ cnt) {
  int e = blockIdx.x * 256 + threadIdx.x;
  if (e < NE) atomicAdd(&cnt[dst[e]], 1);
}

constexpr int SCAN_ELEMS = 1024;  // per block (256 threads x 4)
__global__ void k_scan1(const int* __restrict__ cnt, int* __restrict__ base, int* __restrict__ aux, int n) {
  __shared__ int sw[256];
  int b = blockIdx.x, t = threadIdx.x;
  int i0 = b * SCAN_ELEMS + t * 4;
  int v[4]; int s = 0;
  #pragma unroll
  for (int j = 0; j < 4; j++) { int idx = i0 + j; v[j] = (idx < n) ? cnt[idx] : 0; s += v[j]; }
  sw[t] = s; __syncthreads();
  for (int d = 1; d < 256; d <<= 1) {
    int val = (t >= d) ? sw[t - d] : 0;
    __syncthreads();
    sw[t] += val;
    __syncthreads();
  }
  int run = (t > 0) ? sw[t - 1] : 0;
  #pragma unroll
  for (int j = 0; j < 4; j++) { int idx = i0 + j; if (idx < n) base[idx] = run; run += v[j]; }
  if (t == 255) aux[b] = sw[255];
}

__global__ void k_scan2(int* aux, int nb) {
  if (threadIdx.x == 0 && blockIdx.x == 0) {
    int run = 0;
    for (int i = 0; i < nb; i++) { int v = aux[i]; aux[i] = run; run += v; }
  }
}

__global__ void k_scan3(int* __restrict__ base, int* __restrict__ cursor, const int* __restrict__ aux, int n) {
  int i = blockIdx.x * 256 + threadIdx.x;
  if (i < n) { int v = base[i] + aux[i / SCAN_ELEMS]; base[i] = v; cursor[i] = v; }
}

__global__ void k_place(const int* __restrict__ dst, int* __restrict__ cursor, int* __restrict__ perm) {
  int e = blockIdx.x * 256 + threadIdx.x;
  if (e < NE) { int p = atomicAdd(&cursor[dst[e]], 1); perm[p] = e; }
}

// ---------------- fused edge kernel v9: 64 rows/wave, 4 K-sweeps of 128, 2 blocks/CU ----------------
// msg_e = einsum('i,io->o', x[src_e], reshape(lrelu(ea_e@W1+b1)@W2 + b2, [FIN,FOUT]))
// af = 64 rows x 128 K = 64 regs; acc folded per-ct (16 regs); target <=128 total regs.
// B LDS layout: [32 cols][BSTRIDE=272B] -> bank-slot (17*l15+l4) mod 32, <=2-way conflicts.
template <int FIN, int FOUT>
__global__ __launch_bounds__(512, 4)
void k_edge(const float* __restrict__ x, const float* __restrict__ ea,
            const int* __restrict__ srcI,
            const __hip_bfloat16* __restrict__ W1T, const float* __restrict__ b1,
            const __hip_bfloat16* __restrict__ W2T, const float* __restrict__ b2,
            __hip_bfloat16* __restrict__ msgb)
{
  static_assert(FOUT == 32 || FOUT == 16, "");
  constexpr int TM = 512;          // edges per block (8 waves x 64)
  constexpr int CG = 32;           // cols per staged group
  constexpr int NCGI = 16;
  constexpr int KH = 128;          // K per sweep
  constexpr int NSW = 4;           // sweeps
  constexpr int NKS = 4;           // 32-K steps per sweep
  constexpr int NOT = FOUT / 16;
  constexpr int BSTRIDE = 272;     // 16 data slots + 1 pad slot (16B each)
  constexpr int XLDS = TM + 8;

  // union: g-phase = 8 waves x 4KB private chunks (32KB); cgi loop = double bbuf (2x8.5KB)
  __shared__ __align__(16) char ubuf[32768];
  __shared__ __align__(16) __hip_bfloat16 xlt[FIN][XLDS];   // transposed x, bf16 (wave-private cols)
  __shared__ float b1l[512];
  __shared__ float b2l[512];

  const int tid = threadIdx.x;
  const int lane = tid & 63, w = tid >> 6;
  const int l15 = lane & 15, l4 = lane >> 4;
  const int e0 = blockIdx.x * TM;
  const int rem = min(TM, NE - e0);
  const int wrow0 = w * 64;

  // ---- prologue: one edge per thread; b1/b2 -> LDS ----
  b1l[tid] = b1[tid];
  b2l[tid] = b2[tid];
  union { s16x8 v; int i4[4]; } earow;
  {
    int er = e0 + min(tid, rem - 1);
    float4 v0 = *(const float4*)(ea + (size_t)er * 8);
    float4 v1 = *(const float4*)(ea + (size_t)er * 8 + 4);
    __hip_bfloat16* p = (__hip_bfloat16*)&earow;
    p[0] = __float2bfloat16(v0.x); p[1] = __float2bfloat16(v0.y);
    p[2] = __float2bfloat16(v0.z); p[3] = __float2bfloat16(v0.w);
    p[4] = __float2bfloat16(v1.x); p[5] = __float2bfloat16(v1.y);
    p[6] = __float2bfloat16(v1.z); p[7] = __float2bfloat16(v1.w);
    int s = srcI[er];
    #pragma unroll
    for (int q = 0; q < FIN / 4; q++) {
      float4 xv4 = *(const float4*)(x + (size_t)s * FIN + q * 4);
      xlt[q * 4 + 0][tid] = __float2bfloat16(xv4.x);
      xlt[q * 4 + 1][tid] = __float2bfloat16(xv4.y);
      xlt[q * 4 + 2][tid] = __float2bfloat16(xv4.z);
      xlt[q * 4 + 3][tid] = __float2bfloat16(xv4.w);
    }
  }
  __syncthreads();   // b1l/b2l visible (xlt is wave-private)

  f32x4 msg[4][NOT];
  #pragma unroll
  for (int rt = 0; rt < 4; rt++)
    #pragma unroll
    for (int ot = 0; ot < NOT; ot++) msg[rt][ot] = (f32x4)(0.f);

  s16x8 af[NKS][4];   // A fragments: 64 rows x 128 K = 64 regs, resident
  // staging index precompute: thread covers (col tid>>4, slot tid&15)
  const int st_n = tid >> 4, st_s = tid & 15;
  const char* W2Tb = (const char*)W2T;

  for (int sw = 0; sw < NSW; ++sw) {
    // ---- g-phase: g = lrelu(ea@W1+b1), 64 rows x K-chunk 128, 4KB wave-private sub-chunks ----
    s16x8 afe[4];
    #pragma unroll
    for (int rt = 0; rt < 4; rt++) {
      union { s16x8 v; int i4[4]; } t2;
      #pragma unroll
      for (int q = 0; q < 4; q++) t2.i4[q] = __shfl(earow.i4[q], rt * 16 + l15);
      afe[rt] = (lane < 16) ? t2.v : (s16x8)0;
    }
    char* gme = ubuf + w * 4096;
    #pragma unroll
    for (int kst = 0; kst < NKS; ++kst) {
      #pragma unroll
      for (int ct = 0; ct < 2; ++ct) {
        int c = sw * KH + kst * 32 + ct * 16 + l15;
        s16x8 bw = *(const s16x8*)(W1T + c * 8);
        bw = (lane < 16) ? bw : (s16x8)0;
        float b1v = b1l[c];
        #pragma unroll
        for (int rt = 0; rt < 4; rt++) {
          f32x4 d = __builtin_amdgcn_mfma_f32_16x16x32_bf16(afe[rt], bw, (f32x4)(0.f), 0, 0, 0);
          #pragma unroll
          for (int r = 0; r < 4; r++) {
            int rloc = rt * 16 + l4 * 4 + r;
            float gv = d[r] + b1v;
            gv = gv >= 0.f ? gv : 0.01f * gv;
            int byt = (rloc * 64 + (ct * 16 + l15) * 2) ^ (((rloc >> 2) & 3) << 4);
            *(__hip_bfloat16*)(gme + byt) = __float2bfloat16(gv);
          }
        }
      }
      // read this kstep's A-fragments (wave-private, in-order)
      #pragma unroll
      for (int rt = 0; rt < 4; rt++) {
        int rloc2 = rt * 16 + l15;
        int byt = (rloc2 * 64 + l4 * 16) ^ (((rloc2 >> 2) & 3) << 4);
        af[kst][rt] = *(const s16x8*)(gme + byt);
      }
    }
    // pin A fragments in regs
    #pragma unroll
    for (int kst = 0; kst < NKS; kst++)
      #pragma unroll
      for (int rt = 0; rt < 4; rt++)
        asm volatile("" : "+v"(af[kst][rt]));

    // load first col-group for this sweep
    int4v sr = *(const int4v*)(W2Tb + (size_t)st_n * 1024 + sw * 256 + st_s * 16);
    __syncthreads();               // all g reads done; ubuf becomes bbuf
    *(int4v*)(ubuf + st_n * BSTRIDE + st_s * 16) = sr;
    __syncthreads();

    for (int cgi = 0; cgi < NCGI; ++cgi) {
      if (cgi + 1 < NCGI)
        sr = *(const int4v*)(W2Tb + (size_t)((cgi + 1) * CG + st_n) * 1024 + sw * 256 + st_s * 16);
      const char* bb = ubuf + (cgi & 1) * (CG * BSTRIDE);
      const int rdbase = l15 * BSTRIDE + l4 * 16;

      #pragma unroll
      for (int ct = 0; ct < 2; ++ct) {
        f32x4 acc[4];
        acc[0] = (f32x4)(0.f); acc[1] = (f32x4)(0.f);
        acc[2] = (f32x4)(0.f); acc[3] = (f32x4)(0.f);
        #pragma unroll
        for (int kst = 0; kst < NKS; ++kst) {
          const s16x8 bw = *(const s16x8*)(bb + ct * (16 * BSTRIDE) + rdbase + kst * 64);
          #pragma unroll
          for (int rt = 0; rt < 4; rt++)
            acc[rt] = __builtin_amdgcn_mfma_f32_16x16x32_bf16(af[kst][rt], bw, acc[rt], 0, 0, 0);
        }
        // fold: +b2 (sweep 0 only), scale by x[e, i(col)], into msg
        float b2v = (sw == 0) ? b2l[cgi * CG + ct * 16 + l15] : 0.f;
        const int iv = (FOUT == 32) ? cgi : (cgi * 2 + ct);
        const int ot = (FOUT == 32) ? ct : 0;
        #pragma unroll
        for (int rt = 0; rt < 4; rt++) {
          int rbase = wrow0 + rt * 16 + l4 * 4;
          ushort4 xv = *(const ushort4*)(&xlt[iv][rbase]);
          msg[rt][ot][0] += bfbits2f(xv.x) * (acc[rt][0] + b2v);
          msg[rt][ot][1] += bfbits2f(xv.y) * (acc[rt][1] + b2v);
          msg[rt][ot][2] += bfbits2f(xv.z) * (acc[rt][2] + b2v);
          msg[rt][ot][3] += bfbits2f(xv.w) * (acc[rt][3] + b2v);
        }
      }
      if (cgi + 1 < NCGI)   // write prefetched group to the other buffer (safe: all waves past prev barrier)
        *(int4v*)(ubuf + ((cgi + 1) & 1) * (CG * BSTRIDE) + st_n * BSTRIDE + st_s * 16) = sr;
      __syncthreads();
    }
  }

  // ---- dense coalesced bf16 store ----
  #pragma unroll
  for (int rt = 0; rt < 4; rt++)
    #pragma unroll
    for (int r = 0; r < 4; r++) {
      int row = wrow0 + rt * 16 + l4 * 4 + r;
      if (row < rem) {
        #pragma unroll
        for (int ot = 0; ot < NOT; ot++)
          msgb[(size_t)(e0 + row) * FOUT + ot * 16 + l15] = __float2bfloat16(msg[rt][ot][r]);
      }
    }
}

// ---------------- fused gather + root + bias: h = mean(msg@dst) + x@root + bias ----------------
template <int FIN, int FOUT>
__global__ void k_node_agg(const __hip_bfloat16* __restrict__ msgb, const int* __restrict__ perm,
                           const int* __restrict__ base,
                           const float* __restrict__ x,
                           const float* __restrict__ root,   // [FIN][FOUT]
                           const float* __restrict__ bias,
                           float* __restrict__ h)
{
  __shared__ float rl[FIN * FOUT];
  constexpr int NPB = 256 / FOUT;
  int t = threadIdx.x;
  for (int i = t; i < FIN * FOUT; i += 256) rl[i] = root[i];
  __syncthreads();
  int n = blockIdx.x * NPB + t / FOUT;
  int o = t % FOUT;
  if (n >= NN) return;
  int s = base[n];
  int e = (n + 1 < NN) ? base[n + 1] : NE;
  float sum = 0.f;
  for (int j = s; j < e; j++)
    sum += __bfloat162float(msgb[(size_t)perm[j] * FOUT + o]);
  float acc = sum / fmaxf((float)(e - s), 1.f) + bias[o];
  #pragma unroll
  for (int i = 0; i < FIN; i++)
    acc += x[(size_t)n * FIN + i] * rl[i * FOUT + o];
  h[(size_t)n * FOUT + o] = acc;
}

// ---------------- BN stats: per-column sum & sumsq ----------------
template <int FOUT>
__global__ void k_stats(const float* __restrict__ h, float* __restrict__ ssum, float* __restrict__ ssq) {
  constexpr int RPB = 256 / FOUT;
  int t = threadIdx.x;
  int o = t % FOUT, rr = t / FOUT;
  float v = 0.f, v2 = 0.f;
  for (int r = blockIdx.x * RPB + rr; r < NN; r += gridDim.x * RPB) {
    float y = h[(size_t)r * FOUT + o];
    v += y; v2 += y * y;
  }
  #pragma unroll
  for (int d = FOUT; d < 64; d <<= 1) { v += __shfl_xor(v, d); v2 += __shfl_xor(v2, d); }
  __shared__ float sv[4][32], sq[4][32];
  int wv = t >> 6, ln = t & 63;
  if (ln < FOUT) { sv[wv][ln] = v; sq[wv][ln] = v2; }
  __syncthreads();
  if (t < FOUT) {
    float a = 0.f, b = 0.f;
    #pragma unroll
    for (int w2 = 0; w2 < 4; w2++) { a += sv[w2][t]; b += sq[w2][t]; }
    atomicAdd(&ssum[t], a);
    atomicAdd(&ssq[t], b);
  }
}

// ---------------- BN apply (+optional lrelu) ----------------
template <int FOUT, bool LRELU>
__global__ void k_bn(const float* __restrict__ h, const float* __restrict__ ssum,
                     const float* __restrict__ ssq, const float* __restrict__ gamma,
                     const float* __restrict__ beta, float* __restrict__ out)
{
  int idx = blockIdx.x * 256 + threadIdx.x;
  if (idx * 4 >= NN * FOUT) return;
  float4 v = *(const float4*)(h + (size_t)idx * 4);
  float r[4] = {v.x, v.y, v.z, v.w};
  #pragma unroll
  for (int j = 0; j < 4; j++) {
    int o = (idx * 4 + j) % FOUT;
    float mu = ssum[o] * (1.f / NN);
    float var = ssq[o] * (1.f / NN) - mu * mu;
    float sc = rsqrtf(var + BN_EPS) * gamma[o];
    float y = (r[j] - mu) * sc + beta[o];
    if (LRELU) y = lrelu_f(y);
    r[j] = y;
  }
  *(float4*)(out + (size_t)idx * 4) = make_float4(r[0], r[1], r[2], r[3]);
}

extern "C" void kernel_launch(void* const* d_in, const int* in_sizes, int n_in,
                              void* d_out, int out_size, void* d_ws, size_t ws_size,
                              hipStream_t stream)
{
  const float* x0    = (const float*)d_in[0];
  const float* ea    = (const float*)d_in[1];
  const int*   ei    = (const int*)d_in[2];
  const float* W1_0  = (const float*)d_in[3];
  const float* b1_0  = (const float*)d_in[4];
  const float* W2_0  = (const float*)d_in[5];
  const float* b2_0  = (const float*)d_in[6];
  const float* root0 = (const float*)d_in[7];
  const float* bias0 = (const float*)d_in[8];
  const float* gam0  = (const float*)d_in[9];
  const float* bet0  = (const float*)d_in[10];
  const float* W1_1  = (const float*)d_in[11];
  const float* b1_1  = (const float*)d_in[12];
  const float* W2_1  = (const float*)d_in[13];
  const float* b2_1  = (const float*)d_in[14];
  const float* root1 = (const float*)d_in[15];
  const float* bias1 = (const float*)d_in[16];
  const float* gam1  = (const float*)d_in[17];
  const float* bet1  = (const float*)d_in[18];
  const int* srcI = ei;
  const int* dstI = ei + NE;

  char* ws = (char*)d_ws;
  size_t off = 0;
  auto alloc = [&](size_t bytes) { char* p = ws + off; off += (bytes + 255) & ~(size_t)255; return p; };
  // ---- zeroed region ----
  int*   cnt   = (int*)alloc(50048 * 4);
  float* ssum0 = (float*)alloc(32 * 4);
  float* ssq0  = (float*)alloc(32 * 4);
  float* ssum1 = (float*)alloc(16 * 4);
  float* ssq1  = (float*)alloc(16 * 4);
  size_t zero_bytes = off;
  // ---- rest ----
  int*   base   = (int*)alloc(50048 * 4);
  int*   cursor = (int*)alloc(50048 * 4);
  int*   aux    = (int*)alloc(64 * 4);
  int*   perm   = (int*)alloc((size_t)NE * 4);
  __hip_bfloat16* msgb = (__hip_bfloat16*)alloc((size_t)NE * 32 * 2);  // reused for layer1 (16)
  float* h0 = (float*)alloc((size_t)NN * 32 * 4);
  float* h1 = (float*)alloc((size_t)NN * 16 * 4);
  float* x1 = (float*)alloc((size_t)NN * 32 * 4);
  __hip_bfloat16* W2T0 = (__hip_bfloat16*)alloc(512 * 512 * 2);
  __hip_bfloat16* W2T1 = (__hip_bfloat16*)alloc(512 * 512 * 2);
  __hip_bfloat16* W1T0 = (__hip_bfloat16*)alloc(512 * 8 * 2);
  __hip_bfloat16* W1T1 = (__hip_bfloat16*)alloc(512 * 8 * 2);

  hipMemsetAsync(d_ws, 0, zero_bytes, stream);

  // weight prep (merged across layers)
  k_transpose_w2<<<dim3(256, 2), 256, 0, stream>>>(W2_0, W2_1, W2T0, W2T1);
  k_transpose_w1<<<dim3(16, 2), 256, 0, stream>>>(W1_0, W1_1, W1T0, W1T1);

  // counting sort by dst (shared by both layers)
  constexpr int NSB = (NN + SCAN_ELEMS - 1) / SCAN_ELEMS;  // 49
  k_count<<<(NE + 255) / 256, 256, 0, stream>>>(dstI, cnt);
  k_scan1<<<NSB, 256, 0, stream>>>(cnt, base, aux, NN);
  k_scan2<<<1, 64, 0, stream>>>(aux, NSB);
  k_scan3<<<(NN + 255) / 256, 256, 0, stream>>>(base, cursor, aux, NN);
  k_place<<<(NE + 255) / 256, 256, 0, stream>>>(dstI, cursor, perm);

  constexpr int TM = 512;
  // layer 0
  k_edge<16, 32><<<(NE + TM - 1) / TM, 512, 0, stream>>>(x0, ea, srcI, W1T0, b1_0, W2T0, b2_0, msgb);
  k_node_agg<16, 32><<<(NN + 7) / 8, 256, 0, stream>>>(msgb, perm, base, x0, root0, bias0, h0);
  k_stats<32><<<128, 256, 0, stream>>>(h0, ssum0, ssq0);
  k_bn<32, true><<<((NN * 32 / 4) + 255) / 256, 256, 0, stream>>>(h0, ssum0, ssq0, gam0, bet0, x1);

  // layer 1
  k_edge<32, 16><<<(NE + TM - 1) / TM, 512, 0, stream>>>(x1, ea, srcI, W1T1, b1_1, W2T1, b2_1, msgb);
  k_node_agg<32, 16><<<(NN + 15) / 16, 256, 0, stream>>>(msgb, perm, base, x1, root1, bias1, h1);
  k_stats<16><<<128, 256, 0, stream>>>(h1, ssum1, ssq1);
  k_bn<16, false><<<((NN * 16 / 4) + 255) / 256, 256, 0, stream>>>(h1, ssum1, ssq1, gam1, bet1, (float*)d_out);
}

// Round 10
// 472.808 us; speedup vs baseline: 2.3212x; 2.3212x over previous
//
#include <hip/hip_runtime.h>
#include <hip/hip_bf16.h>

typedef __attribute__((ext_vector_type(4))) float f32x4;
typedef __attribute__((ext_vector_type(8))) short s16x8;
typedef __attribute__((ext_vector_type(4))) int int4v;

#define DEVI __device__ __forceinline__

constexpr int NN = 50000;
constexpr int NE = 200000;
constexpr float BN_EPS = 1e-5f;

DEVI float bfbits2f(unsigned v) { union { unsigned u; float f; } t; t.u = v << 16; return t.f; }
DEVI float lrelu_f(float v) { return v >= 0.f ? v : 0.01f * v; }

// ---------------- prep: W2T[n][k] = bf16(W2[k][n]) for both layers ----------------
__global__ void k_transpose_w2(const float* __restrict__ A0, const float* __restrict__ A1,
                               __hip_bfloat16* __restrict__ T0, __hip_bfloat16* __restrict__ T1) {
  const float* W2 = blockIdx.y ? A1 : A0;
  __hip_bfloat16* W2T = blockIdx.y ? T1 : T0;
  __shared__ float tile[32][33];
  int bx = blockIdx.x % 16, by = blockIdx.x / 16;
  int t = threadIdx.x;
  int r = t / 32, c = t % 32;
  for (int rr = r; rr < 32; rr += 8)
    tile[rr][c] = W2[(size_t)(by * 32 + rr) * 512 + bx * 32 + c];
  __syncthreads();
  for (int rr = r; rr < 32; rr += 8)
    W2T[(size_t)(bx * 32 + rr) * 512 + by * 32 + c] = __float2bfloat16(tile[c][rr]);
}

// W1T[n][k] = bf16(W1[k][n]); W1 is [8][512]
__global__ void k_transpose_w1(const float* __restrict__ A0, const float* __restrict__ A1,
                               __hip_bfloat16* __restrict__ T0, __hip_bfloat16* __restrict__ T1) {
  const float* W1 = blockIdx.y ? A1 : A0;
  __hip_bfloat16* W1T = blockIdx.y ? T1 : T0;
  int tid = blockIdx.x * 256 + threadIdx.x;
  if (tid < 8 * 512) {
    int k = tid / 512, n = tid % 512;
    W1T[n * 8 + k] = __float2bfloat16(W1[tid]);
  }
}

// ---------------- counting sort by dst -> perm ----------------
__global__ void k_count(const int* __restrict__ dst, int* __restrict__ cnt) {
  int e = blockIdx.x * 256 + threadIdx.x;
  if (e < NE) atomicAdd(&cnt[dst[e]], 1);
}

constexpr int SCAN_ELEMS = 1024;  // per block (256 threads x 4)
__global__ void k_scan1(const int* __restrict__ cnt, int* __restrict__ base, int* __restrict__ aux, int n) {
  __shared__ int sw[256];
  int b = blockIdx.x, t = threadIdx.x;
  int i0 = b * SCAN_ELEMS + t * 4;
  int v[4]; int s = 0;
  #pragma unroll
  for (int j = 0; j < 4; j++) { int idx = i0 + j; v[j] = (idx < n) ? cnt[idx] : 0; s += v[j]; }
  sw[t] = s; __syncthreads();
  for (int d = 1; d < 256; d <<= 1) {
    int val = (t >= d) ? sw[t - d] : 0;
    __syncthreads();
    sw[t] += val;
    __syncthreads();
  }
  int run = (t > 0) ? sw[t - 1] : 0;
  #pragma unroll
  for (int j = 0; j < 4; j++) { int idx = i0 + j; if (idx < n) base[idx] = run; run += v[j]; }
  if (t == 255) aux[b] = sw[255];
}

__global__ void k_scan2(int* aux, int nb) {
  if (threadIdx.x == 0 && blockIdx.x == 0) {
    int run = 0;
    for (int i = 0; i < nb; i++) { int v = aux[i]; aux[i] = run; run += v; }
  }
}

__global__ void k_scan3(int* __restrict__ base, int* __restrict__ cursor, const int* __restrict__ aux, int n) {
  int i = blockIdx.x * 256 + threadIdx.x;
  if (i < n) { int v = base[i] + aux[i / SCAN_ELEMS]; base[i] = v; cursor[i] = v; }
}

__global__ void k_place(const int* __restrict__ dst, int* __restrict__ cursor, int* __restrict__ perm) {
  int e = blockIdx.x * 256 + threadIdx.x;
  if (e < NE) { int p = atomicAdd(&cursor[dst[e]], 1); perm[p] = e; }
}

// ---------------- fused edge kernel v10: 4-wave blocks, KH=64, <=128 regs, v3 XOR layouts ----------------
// msg_e = einsum('i,io->o', x[src_e], reshape(lrelu(ea_e@W1+b1)@W2 + b2, [FIN,FOUT]))
template <int FIN, int FOUT>
__global__ __launch_bounds__(256, 4)
void k_edge(const float* __restrict__ x, const float* __restrict__ ea,
            const int* __restrict__ srcI,
            const __hip_bfloat16* __restrict__ W1T, const float* __restrict__ b1,
            const __hip_bfloat16* __restrict__ W2T, const float* __restrict__ b2,
            __hip_bfloat16* __restrict__ msgb)
{
  static_assert(FOUT == 32 || FOUT == 16, "");
  constexpr int TM = 256;          // edges per block (4 waves x 64)
  constexpr int CG = 32;           // cols per staged group
  constexpr int NCGI = 16;
  constexpr int KH = 64;           // K per sweep
  constexpr int NSW = 8;           // sweeps
  constexpr int NOT = FOUT / 16;

  __shared__ __align__(16) char gbuf[4][4096];            // per-wave 32row x 64k chunk, XOR (row&7)<<4
  __shared__ __align__(16) char bbuf[2][CG * 128];        // 2 x 4KB: col stride 128B, slot^(col&7)
  __shared__ __align__(16) __hip_bfloat16 xlt[FIN][TM];   // transposed x (bf16)

  const int tid = threadIdx.x;
  const int lane = tid & 63, w = tid >> 6;   // 4 waves
  const int l15 = lane & 15, l4 = lane >> 4;
  const int e0 = blockIdx.x * TM;
  const int rem = min(TM, NE - e0);
  const int wrow0 = w * 64;

  // ---- prologue: one edge per thread ----
  union { s16x8 v; int i4[4]; } earow;
  {
    int er = e0 + min(tid, rem - 1);
    float4 v0 = *(const float4*)(ea + (size_t)er * 8);
    float4 v1 = *(const float4*)(ea + (size_t)er * 8 + 4);
    __hip_bfloat16* p = (__hip_bfloat16*)&earow;
    p[0] = __float2bfloat16(v0.x); p[1] = __float2bfloat16(v0.y);
    p[2] = __float2bfloat16(v0.z); p[3] = __float2bfloat16(v0.w);
    p[4] = __float2bfloat16(v1.x); p[5] = __float2bfloat16(v1.y);
    p[6] = __float2bfloat16(v1.z); p[7] = __float2bfloat16(v1.w);
    int s = srcI[er];
    #pragma unroll
    for (int q = 0; q < FIN / 4; q++) {
      float4 xv4 = *(const float4*)(x + (size_t)s * FIN + q * 4);
      xlt[q * 4 + 0][tid] = __float2bfloat16(xv4.x);
      xlt[q * 4 + 1][tid] = __float2bfloat16(xv4.y);
      xlt[q * 4 + 2][tid] = __float2bfloat16(xv4.z);
      xlt[q * 4 + 3][tid] = __float2bfloat16(xv4.w);
    }
  }

  f32x4 msg[4][NOT];
  #pragma unroll
  for (int rt = 0; rt < 4; rt++)
    #pragma unroll
    for (int ot = 0; ot < NOT; ot++) msg[rt][ot] = (f32x4)(0.f);

  s16x8 af[2][4];   // A fragments: [kst][rt], 64 rows x 64 K = 32 regs
  const int st_col = tid >> 3, st_s = tid & 7;
  const int st_dst = st_col * 128 + ((st_s ^ (st_col & 7)) << 4);
  const char* W2Tb = (const char*)W2T;
  char* gme = gbuf[w];

  for (int sw = 0; sw < NSW; ++sw) {
    // prefetch first col-group of this sweep (hides under g-phase)
    int4v sr = *(const int4v*)(W2Tb + (size_t)st_col * 1024 + sw * 128 + st_s * 16);

    // ---- g-phase: g = lrelu(ea@W1+b1), 64 rows x 64 k, wave-private (no barriers) ----
    #pragma unroll
    for (int h = 0; h < 2; ++h) {
      s16x8 afe[2];
      #pragma unroll
      for (int rt2 = 0; rt2 < 2; rt2++) {
        union { s16x8 v; int i4[4]; } t2;
        #pragma unroll
        for (int q = 0; q < 4; q++) t2.i4[q] = __shfl(earow.i4[q], (h * 2 + rt2) * 16 + l15);
        afe[rt2] = (lane < 16) ? t2.v : (s16x8)0;
      }
      #pragma unroll
      for (int ct = 0; ct < 4; ++ct) {
        int c = sw * KH + ct * 16 + l15;
        s16x8 bw = *(const s16x8*)(W1T + c * 8);
        bw = (lane < 16) ? bw : (s16x8)0;
        float b1v = b1[c];
        #pragma unroll
        for (int rt2 = 0; rt2 < 2; rt2++) {
          f32x4 d = __builtin_amdgcn_mfma_f32_16x16x32_bf16(afe[rt2], bw, (f32x4)(0.f), 0, 0, 0);
          #pragma unroll
          for (int r = 0; r < 4; r++) {
            int rloc = rt2 * 16 + l4 * 4 + r;   // 0..31 within half
            float gv = d[r] + b1v;
            gv = gv >= 0.f ? gv : 0.01f * gv;
            int byt = (rloc * 128 + (ct * 16 + l15) * 2) ^ ((rloc & 7) << 4);
            *(__hip_bfloat16*)(gme + byt) = __float2bfloat16(gv);
          }
        }
      }
      #pragma unroll
      for (int rt2 = 0; rt2 < 2; rt2++)
        #pragma unroll
        for (int kst = 0; kst < 2; kst++) {
          int rloc = rt2 * 16 + l15;
          int byt = (rloc * 128 + (kst * 64 + l4 * 16)) ^ ((rloc & 7) << 4);
          af[kst][h * 2 + rt2] = *(const s16x8*)(gme + byt);
        }
    }
    // pin A fragments in regs
    #pragma unroll
    for (int kst = 0; kst < 2; kst++)
      #pragma unroll
      for (int rt = 0; rt < 4; rt++)
        asm volatile("" : "+v"(af[kst][rt]));

    // stage first col-group (prev sweep's readers all passed their last barrier)
    *(int4v*)(&bbuf[0][st_dst]) = sr;
    __syncthreads();

    for (int cgi = 0; cgi < NCGI; ++cgi) {
      if (cgi + 1 < NCGI)
        sr = *(const int4v*)(W2Tb + (size_t)((cgi + 1) * CG + st_col) * 1024 + sw * 128 + st_s * 16);
      const char* bb = bbuf[cgi & 1];

      #pragma unroll
      for (int ct = 0; ct < 2; ++ct) {
        const int c = ct * 16 + l15;
        const int cbase = c * 128;
        const int csw = (c & 7);
        f32x4 acc[4];
        acc[0] = (f32x4)(0.f); acc[1] = (f32x4)(0.f);
        acc[2] = (f32x4)(0.f); acc[3] = (f32x4)(0.f);
        #pragma unroll
        for (int kst = 0; kst < 2; ++kst) {
          const s16x8 bw = *(const s16x8*)(bb + cbase + (((kst * 4 + l4) ^ csw) << 4));
          #pragma unroll
          for (int rt = 0; rt < 4; rt++)
            acc[rt] = __builtin_amdgcn_mfma_f32_16x16x32_bf16(af[kst][rt], bw, acc[rt], 0, 0, 0);
        }
        // fold: +b2 (sweep 0 only), scale by x[e, i(col)], into msg
        float b2v = (sw == 0) ? b2[cgi * CG + ct * 16 + l15] : 0.f;
        const int iv = (FOUT == 32) ? cgi : (cgi * 2 + ct);
        const int ot = (FOUT == 32) ? ct : 0;
        #pragma unroll
        for (int rt = 0; rt < 4; rt++) {
          int rbase = wrow0 + rt * 16 + l4 * 4;
          ushort4 xv = *(const ushort4*)(&xlt[iv][rbase]);
          msg[rt][ot][0] += bfbits2f(xv.x) * (acc[rt][0] + b2v);
          msg[rt][ot][1] += bfbits2f(xv.y) * (acc[rt][1] + b2v);
          msg[rt][ot][2] += bfbits2f(xv.z) * (acc[rt][2] + b2v);
          msg[rt][ot][3] += bfbits2f(xv.w) * (acc[rt][3] + b2v);
        }
      }
      if (cgi + 1 < NCGI)   // write prefetched group to the other buffer
        *(int4v*)(&bbuf[(cgi + 1) & 1][st_dst]) = sr;
      __syncthreads();
    }
  }

  // ---- dense coalesced bf16 store ----
  #pragma unroll
  for (int rt = 0; rt < 4; rt++)
    #pragma unroll
    for (int r = 0; r < 4; r++) {
      int row = wrow0 + rt * 16 + l4 * 4 + r;
      if (row < rem) {
        #pragma unroll
        for (int ot = 0; ot < NOT; ot++)
          msgb[(size_t)(e0 + row) * FOUT + ot * 16 + l15] = __float2bfloat16(msg[rt][ot][r]);
      }
    }
}

// ---------------- fused gather + root + bias: h = mean(msg@dst) + x@root + bias ----------------
template <int FIN, int FOUT>
__global__ void k_node_agg(const __hip_bfloat16* __restrict__ msgb, const int* __restrict__ perm,
                           const int* __restrict__ base,
                           const float* __restrict__ x,
                           const float* __restrict__ root,   // [FIN][FOUT]
                           const float* __restrict__ bias,
                           float* __restrict__ h)
{
  __shared__ float rl[FIN * FOUT];
  constexpr int NPB = 256 / FOUT;
  int t = threadIdx.x;
  for (int i = t; i < FIN * FOUT; i += 256) rl[i] = root[i];
  __syncthreads();
  int n = blockIdx.x * NPB + t / FOUT;
  int o = t % FOUT;
  if (n >= NN) return;
  int s = base[n];
  int e = (n + 1 < NN) ? base[n + 1] : NE;
  float sum = 0.f;
  for (int j = s; j < e; j++)
    sum += __bfloat162float(msgb[(size_t)perm[j] * FOUT + o]);
  float acc = sum / fmaxf((float)(e - s), 1.f) + bias[o];
  #pragma unroll
  for (int i = 0; i < FIN; i++)
    acc += x[(size_t)n * FIN + i] * rl[i * FOUT + o];
  h[(size_t)n * FOUT + o] = acc;
}

// ---------------- BN stats: per-column sum & sumsq ----------------
template <int FOUT>
__global__ void k_stats(const float* __restrict__ h, float* __restrict__ ssum, float* __restrict__ ssq) {
  constexpr int RPB = 256 / FOUT;
  int t = threadIdx.x;
  int o = t % FOUT, rr = t / FOUT;
  float v = 0.f, v2 = 0.f;
  for (int r = blockIdx.x * RPB + rr; r < NN; r += gridDim.x * RPB) {
    float y = h[(size_t)r * FOUT + o];
    v += y; v2 += y * y;
  }
  #pragma unroll
  for (int d = FOUT; d < 64; d <<= 1) { v += __shfl_xor(v, d); v2 += __shfl_xor(v2, d); }
  __shared__ float sv[4][32], sq[4][32];
  int wv = t >> 6, ln = t & 63;
  if (ln < FOUT) { sv[wv][ln] = v; sq[wv][ln] = v2; }
  __syncthreads();
  if (t < FOUT) {
    float a = 0.f, b = 0.f;
    #pragma unroll
    for (int w2 = 0; w2 < 4; w2++) { a += sv[w2][t]; b += sq[w2][t]; }
    atomicAdd(&ssum[t], a);
    atomicAdd(&ssq[t], b);
  }
}

// ---------------- BN apply (+optional lrelu) ----------------
template <int FOUT, bool LRELU>
__global__ void k_bn(const float* __restrict__ h, const float* __restrict__ ssum,
                     const float* __restrict__ ssq, const float* __restrict__ gamma,
                     const float* __restrict__ beta, float* __restrict__ out)
{
  int idx = blockIdx.x * 256 + threadIdx.x;
  if (idx * 4 >= NN * FOUT) return;
  float4 v = *(const float4*)(h + (size_t)idx * 4);
  float r[4] = {v.x, v.y, v.z, v.w};
  #pragma unroll
  for (int j = 0; j < 4; j++) {
    int o = (idx * 4 + j) % FOUT;
    float mu = ssum[o] * (1.f / NN);
    float var = ssq[o] * (1.f / NN) - mu * mu;
    float sc = rsqrtf(var + BN_EPS) * gamma[o];
    float y = (r[j] - mu) * sc + beta[o];
    if (LRELU) y = lrelu_f(y);
    r[j] = y;
  }
  *(float4*)(out + (size_t)idx * 4) = make_float4(r[0], r[1], r[2], r[3]);
}

extern "C" void kernel_launch(void* const* d_in, const int* in_sizes, int n_in,
                              void* d_out, int out_size, void* d_ws, size_t ws_size,
                              hipStream_t stream)
{
  const float* x0    = (const float*)d_in[0];
  const float* ea    = (const float*)d_in[1];
  const int*   ei    = (const int*)d_in[2];
  const float* W1_0  = (const float*)d_in[3];
  const float* b1_0  = (const float*)d_in[4];
  const float* W2_0  = (const float*)d_in[5];
  const float* b2_0  = (const float*)d_in[6];
  const float* root0 = (const float*)d_in[7];
  const float* bias0 = (const float*)d_in[8];
  const float* gam0  = (const float*)d_in[9];
  const float* bet0  = (const float*)d_in[10];
  const float* W1_1  = (const float*)d_in[11];
  const float* b1_1  = (const float*)d_in[12];
  const float* W2_1  = (const float*)d_in[13];
  const float* b2_1  = (const float*)d_in[14];
  const float* root1 = (const float*)d_in[15];
  const float* bias1 = (const float*)d_in[16];
  const float* gam1  = (const float*)d_in[17];
  const float* bet1  = (const float*)d_in[18];
  const int* srcI = ei;
  const int* dstI = ei + NE;

  char* ws = (char*)d_ws;
  size_t off = 0;
  auto alloc = [&](size_t bytes) { char* p = ws + off; off += (bytes + 255) & ~(size_t)255; return p; };
  // ---- zeroed region ----
  int*   cnt   = (int*)alloc(50048 * 4);
  float* ssum0 = (float*)alloc(32 * 4);
  float* ssq0  = (float*)alloc(32 * 4);
  float* ssum1 = (float*)alloc(16 * 4);
  float* ssq1  = (float*)alloc(16 * 4);
  size_t zero_bytes = off;
  // ---- rest ----
  int*   base   = (int*)alloc(50048 * 4);
  int*   cursor = (int*)alloc(50048 * 4);
  int*   aux    = (int*)alloc(64 * 4);
  int*   perm   = (int*)alloc((size_t)NE * 4);
  __hip_bfloat16* msgb = (__hip_bfloat16*)alloc((size_t)NE * 32 * 2);  // reused for layer1 (16)
  float* h0 = (float*)alloc((size_t)NN * 32 * 4);
  float* h1 = (float*)alloc((size_t)NN * 16 * 4);
  float* x1 = (float*)alloc((size_t)NN * 32 * 4);
  __hip_bfloat16* W2T0 = (__hip_bfloat16*)alloc(512 * 512 * 2);
  __hip_bfloat16* W2T1 = (__hip_bfloat16*)alloc(512 * 512 * 2);
  __hip_bfloat16* W1T0 = (__hip_bfloat16*)alloc(512 * 8 * 2);
  __hip_bfloat16* W1T1 = (__hip_bfloat16*)alloc(512 * 8 * 2);

  hipMemsetAsync(d_ws, 0, zero_bytes, stream);

  // weight prep (merged across layers)
  k_transpose_w2<<<dim3(256, 2), 256, 0, stream>>>(W2_0, W2_1, W2T0, W2T1);
  k_transpose_w1<<<dim3(16, 2), 256, 0, stream>>>(W1_0, W1_1, W1T0, W1T1);

  // counting sort by dst (shared by both layers)
  constexpr int NSB = (NN + SCAN_ELEMS - 1) / SCAN_ELEMS;  // 49
  k_count<<<(NE + 255) / 256, 256, 0, stream>>>(dstI, cnt);
  k_scan1<<<NSB, 256, 0, stream>>>(cnt, base, aux, NN);
  k_scan2<<<1, 64, 0, stream>>>(aux, NSB);
  k_scan3<<<(NN + 255) / 256, 256, 0, stream>>>(base, cursor, aux, NN);
  k_place<<<(NE + 255) / 256, 256, 0, stream>>>(dstI, cursor, perm);

  constexpr int TM = 256;
  // layer 0
  k_edge<16, 32><<<(NE + TM - 1) / TM, 256, 0, stream>>>(x0, ea, srcI, W1T0, b1_0, W2T0, b2_0, msgb);
  k_node_agg<16, 32><<<(NN + 7) / 8, 256, 0, stream>>>(msgb, perm, base, x0, root0, bias0, h0);
  k_stats<32><<<128, 256, 0, stream>>>(h0, ssum0, ssq0);
  k_bn<32, true><<<((NN * 32 / 4) + 255) / 256, 256, 0, stream>>>(h0, ssum0, ssq0, gam0, bet0, x1);

  // layer 1
  k_edge<32, 16><<<(NE + TM - 1) / TM, 256, 0, stream>>>(x1, ea, srcI, W1T1, b1_1, W2T1, b2_1, msgb);
  k_node_agg<32, 16><<<(NN + 15) / 16, 256, 0, stream>>>(msgb, perm, base, x1, root1, bias1, h1);
  k_stats<16><<<128, 256, 0, stream>>>(h1, ssum1, ssq1);
  k_bn<16, false><<<((NN * 16 / 4) + 255) / 256, 256, 0, stream>>>(h1, ssum1, ssq1, gam1, bet1, (float*)d_out);
}

// Round 11
// 392.463 us; speedup vs baseline: 2.7964x; 1.2047x over previous
//
#include <hip/hip_runtime.h>
#include <hip/hip_bf16.h>

typedef __attribute__((ext_vector_type(4))) float f32x4;
typedef __attribute__((ext_vector_type(8))) short s16x8;
typedef __attribute__((ext_vector_type(4))) int int4v;

#define DEVI __device__ __forceinline__

constexpr int NN = 50000;
constexpr int NE = 200000;
constexpr float BN_EPS = 1e-5f;

DEVI float bfbits2f(unsigned v) { union { unsigned u; float f; } t; t.u = v << 16; return t.f; }
DEVI float lrelu_f(float v) { return v >= 0.f ? v : 0.01f * v; }

// ---------------- prep: W2T[n][k] = bf16(W2[k][n]) for both layers ----------------
__global__ void k_transpose_w2(const float* __restrict__ A0, const float* __restrict__ A1,
                               __hip_bfloat16* __restrict__ T0, __hip_bfloat16* __restrict__ T1) {
  const float* W2 = blockIdx.y ? A1 : A0;
  __hip_bfloat16* W2T = blockIdx.y ? T1 : T0;
  __shared__ float tile[32][33];
  int bx = blockIdx.x % 16, by = blockIdx.x / 16;
  int t = threadIdx.x;
  int r = t / 32, c = t % 32;
  for (int rr = r; rr < 32; rr += 8)
    tile[rr][c] = W2[(size_t)(by * 32 + rr) * 512 + bx * 32 + c];
  __syncthreads();
  for (int rr = r; rr < 32; rr += 8)
    W2T[(size_t)(bx * 32 + rr) * 512 + by * 32 + c] = __float2bfloat16(tile[c][rr]);
}

// W1T[n][k] = bf16(W1[k][n]); W1 is [8][512]
__global__ void k_transpose_w1(const float* __restrict__ A0, const float* __restrict__ A1,
                               __hip_bfloat16* __restrict__ T0, __hip_bfloat16* __restrict__ T1) {
  const float* W1 = blockIdx.y ? A1 : A0;
  __hip_bfloat16* W1T = blockIdx.y ? T1 : T0;
  int tid = blockIdx.x * 256 + threadIdx.x;
  if (tid < 8 * 512) {
    int k = tid / 512, n = tid % 512;
    W1T[n * 8 + k] = __float2bfloat16(W1[tid]);
  }
}

// ---------------- counting sort by dst -> perm ----------------
__global__ void k_count(const int* __restrict__ dst, int* __restrict__ cnt) {
  int e = blockIdx.x * 256 + threadIdx.x;
  if (e < NE) atomicAdd(&cnt[dst[e]], 1);
}

constexpr int SCAN_ELEMS = 1024;  // per block (256 threads x 4)
__global__ void k_scan1(const int* __restrict__ cnt, int* __restrict__ base, int* __restrict__ aux, int n) {
  __shared__ int sw[256];
  int b = blockIdx.x, t = threadIdx.x;
  int i0 = b * SCAN_ELEMS + t * 4;
  int v[4]; int s = 0;
  #pragma unroll
  for (int j = 0; j < 4; j++) { int idx = i0 + j; v[j] = (idx < n) ? cnt[idx] : 0; s += v[j]; }
  sw[t] = s; __syncthreads();
  for (int d = 1; d < 256; d <<= 1) {
    int val = (t >= d) ? sw[t - d] : 0;
    __syncthreads();
    sw[t] += val;
    __syncthreads();
  }
  int run = (t > 0) ? sw[t - 1] : 0;
  #pragma unroll
  for (int j = 0; j < 4; j++) { int idx = i0 + j; if (idx < n) base[idx] = run; run += v[j]; }
  if (t == 255) aux[b] = sw[255];
}

__global__ void k_scan2(int* aux, int nb) {
  if (threadIdx.x == 0 && blockIdx.x == 0) {
    int run = 0;
    for (int i = 0; i < nb; i++) { int v = aux[i]; aux[i] = run; run += v; }
  }
}

__global__ void k_scan3(int* __restrict__ base, int* __restrict__ cursor, const int* __restrict__ aux, int n) {
  int i = blockIdx.x * 256 + threadIdx.x;
  if (i < n) { int v = base[i] + aux[i / SCAN_ELEMS]; base[i] = v; cursor[i] = v; }
}

__global__ void k_place(const int* __restrict__ dst, int* __restrict__ cursor, int* __restrict__ perm) {
  int e = blockIdx.x * 256 + threadIdx.x;
  if (e < NE) { int p = atomicAdd(&cursor[dst[e]], 1); perm[p] = e; }
}

// ---------------- fused edge kernel v11: R7 schedule in 4-wave blocks (2 blocks/CU) ----------------
// msg_e = einsum('i,io->o', x[src_e], reshape(lrelu(ea_e@W1+b1)@W2 + b2, [FIN,FOUT]))
// 4 waves x 64 rows; af = 64 rows x 256 K pinned (128 regs); launch_bounds(256,2) -> no spill,
// and two independent blocks co-reside per CU so barrier stalls overlap across blocks.
template <int FIN, int FOUT>
__global__ __launch_bounds__(256, 2)
void k_edge(const float* __restrict__ x, const float* __restrict__ ea,
            const int* __restrict__ srcI,
            const __hip_bfloat16* __restrict__ W1T, const float* __restrict__ b1,
            const __hip_bfloat16* __restrict__ W2T, const float* __restrict__ b2,
            __hip_bfloat16* __restrict__ msgb)
{
  static_assert(FOUT == 32 || FOUT == 16, "");
  constexpr int TM = 256;          // edges per block (4 waves x 64)
  constexpr int CG = 32;           // cols per staged group
  constexpr int NCGI = 16;
  constexpr int KH = 256;          // K per sweep
  constexpr int NKC = 4;           // 64-k chunks per sweep
  constexpr int NOT = FOUT / 16;
  constexpr int XLDS = TM + 8;

  __shared__ __align__(16) char bbuf[2][CG * 512];          // 32KB: col*512B, 16B slot ^ (col&7)
  __shared__ __align__(16) char gbuf[4][4096];              // per-wave 32rowx64k chunks
  __shared__ __align__(16) __hip_bfloat16 xlt[FIN][XLDS];   // transposed x, bf16

  const int tid = threadIdx.x;
  const int lane = tid & 63, w = tid >> 6;   // 4 waves
  const int l15 = lane & 15, l4 = lane >> 4;
  const int e0 = blockIdx.x * TM;
  const int rem = min(TM, NE - e0);
  const int wrow0 = w * 64;

  // ---- prologue: one edge per thread ----
  union { s16x8 v; int i4[4]; } earow;
  {
    int er = e0 + min(tid, rem - 1);
    float4 v0 = *(const float4*)(ea + (size_t)er * 8);
    float4 v1 = *(const float4*)(ea + (size_t)er * 8 + 4);
    __hip_bfloat16* p = (__hip_bfloat16*)&earow;
    p[0] = __float2bfloat16(v0.x); p[1] = __float2bfloat16(v0.y);
    p[2] = __float2bfloat16(v0.z); p[3] = __float2bfloat16(v0.w);
    p[4] = __float2bfloat16(v1.x); p[5] = __float2bfloat16(v1.y);
    p[6] = __float2bfloat16(v1.z); p[7] = __float2bfloat16(v1.w);
    int s = srcI[er];
    #pragma unroll
    for (int q = 0; q < FIN / 4; q++) {
      float4 xv4 = *(const float4*)(x + (size_t)s * FIN + q * 4);
      xlt[q * 4 + 0][tid] = __float2bfloat16(xv4.x);
      xlt[q * 4 + 1][tid] = __float2bfloat16(xv4.y);
      xlt[q * 4 + 2][tid] = __float2bfloat16(xv4.z);
      xlt[q * 4 + 3][tid] = __float2bfloat16(xv4.w);
    }
  }

  f32x4 msg[4][NOT];
  #pragma unroll
  for (int rt = 0; rt < 4; rt++)
    #pragma unroll
    for (int ot = 0; ot < NOT; ot++) msg[rt][ot] = (f32x4)(0.f);

  s16x8 af[NKC][4][2];   // A fragments: 64 rows x 256 K = 128 regs, pinned resident
  // staging: thread covers col (tid>>3), slots (tid&7)+8j -> global 128B-contiguous per 8 lanes,
  // LDS writes 2-way max per 16-lane phase.
  const int st_col = tid >> 3, st_s = tid & 7;
  const char* W2Tb = (const char*)W2T;
  char* gme = gbuf[w];
  int4v sr[4];

  for (int sw = 0; sw < 2; ++sw) {
    // issue first W2T col-group loads early (latency hides under g-phase)
    {
      const char* gp = W2Tb + (size_t)st_col * 1024 + sw * 512;
      #pragma unroll
      for (int j = 0; j < 4; j++) sr[j] = *(const int4v*)(gp + st_s * 16 + j * 128);
    }
    // ---- g-phase: g = lrelu(ea@W1+b1), two 32-row halves, wave-private chunk ----
    s16x8 afe[4];
    #pragma unroll
    for (int rt = 0; rt < 4; rt++) {
      union { s16x8 v; int i4[4]; } t2;
      #pragma unroll
      for (int q = 0; q < 4; q++) t2.i4[q] = __shfl(earow.i4[q], rt * 16 + l15);
      afe[rt] = (lane < 16) ? t2.v : (s16x8)0;
    }
    #pragma unroll
    for (int h = 0; h < 2; ++h) {
      #pragma unroll
      for (int kc = 0; kc < NKC; kc++) {
        #pragma unroll
        for (int ct = 0; ct < 4; ct++) {
          int c = sw * KH + kc * 64 + ct * 16 + l15;
          s16x8 bw = *(const s16x8*)(W1T + c * 8);
          bw = (lane < 16) ? bw : (s16x8)0;
          float b1v = b1[c];
          #pragma unroll
          for (int rt2 = 0; rt2 < 2; rt2++) {
            f32x4 d = __builtin_amdgcn_mfma_f32_16x16x32_bf16(afe[h * 2 + rt2], bw, (f32x4)(0.f), 0, 0, 0);
            #pragma unroll
            for (int r = 0; r < 4; r++) {
              int rloc = rt2 * 16 + l4 * 4 + r;
              float gv = d[r] + b1v;
              gv = gv >= 0.f ? gv : 0.01f * gv;
              int byt = (rloc * 128 + (ct * 16 + l15) * 2) ^ ((rloc & 7) << 4);
              *(__hip_bfloat16*)(gme + byt) = __float2bfloat16(gv);
            }
          }
        }
        #pragma unroll
        for (int rt2 = 0; rt2 < 2; rt2++)
          #pragma unroll
          for (int ks = 0; ks < 2; ks++) {
            int rloc = rt2 * 16 + l15;
            int byt = (rloc * 128 + (ks * 32 + l4 * 8) * 2) ^ ((rloc & 7) << 4);
            af[kc][h * 2 + rt2][ks] = *(const s16x8*)(gme + byt);
          }
      }
    }
    // pin A fragments in regs -- forbids remat-from-LDS sinking
    #pragma unroll
    for (int kc = 0; kc < NKC; kc++)
      #pragma unroll
      for (int rt = 0; rt < 4; rt++)
        #pragma unroll
        for (int ks = 0; ks < 2; ks++)
          asm volatile("" : "+v"(af[kc][rt][ks]));

    // stage first col-group (prev sweep's readers passed their last barrier)
    #pragma unroll
    for (int j = 0; j < 4; j++)
      *(int4v*)(&bbuf[0][st_col * 512 + (((st_s + 8 * j) ^ (st_col & 7)) << 4)]) = sr[j];
    __syncthreads();

    for (int cgi = 0; cgi < NCGI; ++cgi) {
      if (cgi + 1 < NCGI) {   // prefetch next col-group to regs
        const char* gp = W2Tb + (size_t)((cgi + 1) * CG + st_col) * 1024 + sw * 512;
        #pragma unroll
        for (int j = 0; j < 4; j++) sr[j] = *(const int4v*)(gp + st_s * 16 + j * 128);
      }
      const char* bb = bbuf[cgi & 1];
      f32x4 acc[4][2];
      #pragma unroll
      for (int rt = 0; rt < 4; rt++) { acc[rt][0] = (f32x4)(0.f); acc[rt][1] = (f32x4)(0.f); }

      #pragma unroll
      for (int kc = 0; kc < NKC; kc++)
        #pragma unroll
        for (int ct = 0; ct < 2; ct++) {
          const int c = ct * 16 + l15;
          #pragma unroll
          for (int ks = 0; ks < 2; ks++) {
            const int slot = kc * 8 + ks * 4 + l4;
            const s16x8 bw = *(const s16x8*)(bb + c * 512 + ((slot ^ (c & 7)) << 4));
            #pragma unroll
            for (int rt = 0; rt < 4; rt++)
              acc[rt][ct] = __builtin_amdgcn_mfma_f32_16x16x32_bf16(af[kc][rt][ks], bw, acc[rt][ct], 0, 0, 0);
          }
        }

      // epilogue: +b2 (sweep 0 only), scale by x[e, i(col)], fold into msg
      #pragma unroll
      for (int ct = 0; ct < 2; ct++) {
        float b2v = (sw == 0) ? b2[cgi * CG + ct * 16 + l15] : 0.f;
        const int iv = (FOUT == 32) ? cgi : (cgi * 2 + ct);
        const int ot = (FOUT == 32) ? ct : 0;
        #pragma unroll
        for (int rt = 0; rt < 4; rt++) {
          int rbase = wrow0 + rt * 16 + l4 * 4;
          ushort4 xv = *(const ushort4*)(&xlt[iv][rbase]);
          msg[rt][ot][0] += bfbits2f(xv.x) * (acc[rt][ct][0] + b2v);
          msg[rt][ot][1] += bfbits2f(xv.y) * (acc[rt][ct][1] + b2v);
          msg[rt][ot][2] += bfbits2f(xv.z) * (acc[rt][ct][2] + b2v);
          msg[rt][ot][3] += bfbits2f(xv.w) * (acc[rt][ct][3] + b2v);
        }
      }
      if (cgi + 1 < NCGI) {   // write prefetched group to the other buffer
        char* bw2 = bbuf[(cgi + 1) & 1];
        #pragma unroll
        for (int j = 0; j < 4; j++)
          *(int4v*)(&bw2[st_col * 512 + (((st_s + 8 * j) ^ (st_col & 7)) << 4)]) = sr[j];
      }
      __syncthreads();
    }
  }

  // ---- dense coalesced bf16 store ----
  #pragma unroll
  for (int rt = 0; rt < 4; rt++)
    #pragma unroll
    for (int r = 0; r < 4; r++) {
      int row = wrow0 + rt * 16 + l4 * 4 + r;
      if (row < rem) {
        #pragma unroll
        for (int ot = 0; ot < NOT; ot++)
          msgb[(size_t)(e0 + row) * FOUT + ot * 16 + l15] = __float2bfloat16(msg[rt][ot][r]);
      }
    }
}

// ---------------- fused gather + root + bias: h = mean(msg@dst) + x@root + bias ----------------
template <int FIN, int FOUT>
__global__ void k_node_agg(const __hip_bfloat16* __restrict__ msgb, const int* __restrict__ perm,
                           const int* __restrict__ base,
                           const float* __restrict__ x,
                           const float* __restrict__ root,   // [FIN][FOUT]
                           const float* __restrict__ bias,
                           float* __restrict__ h)
{
  __shared__ float rl[FIN * FOUT];
  constexpr int NPB = 256 / FOUT;
  int t = threadIdx.x;
  for (int i = t; i < FIN * FOUT; i += 256) rl[i] = root[i];
  __syncthreads();
  int n = blockIdx.x * NPB + t / FOUT;
  int o = t % FOUT;
  if (n >= NN) return;
  int s = base[n];
  int e = (n + 1 < NN) ? base[n + 1] : NE;
  float sum = 0.f;
  for (int j = s; j < e; j++)
    sum += __bfloat162float(msgb[(size_t)perm[j] * FOUT + o]);
  float acc = sum / fmaxf((float)(e - s), 1.f) + bias[o];
  #pragma unroll
  for (int i = 0; i < FIN; i++)
    acc += x[(size_t)n * FIN + i] * rl[i * FOUT + o];
  h[(size_t)n * FOUT + o] = acc;
}

// ---------------- BN stats: per-column sum & sumsq ----------------
template <int FOUT>
__global__ void k_stats(const float* __restrict__ h, float* __restrict__ ssum, float* __restrict__ ssq) {
  constexpr int RPB = 256 / FOUT;
  int t = threadIdx.x;
  int o = t % FOUT, rr = t / FOUT;
  float v = 0.f, v2 = 0.f;
  for (int r = blockIdx.x * RPB + rr; r < NN; r += gridDim.x * RPB) {
    float y = h[(size_t)r * FOUT + o];
    v += y; v2 += y * y;
  }
  #pragma unroll
  for (int d = FOUT; d < 64; d <<= 1) { v += __shfl_xor(v, d); v2 += __shfl_xor(v2, d); }
  __shared__ float sv[4][32], sq[4][32];
  int wv = t >> 6, ln = t & 63;
  if (ln < FOUT) { sv[wv][ln] = v; sq[wv][ln] = v2; }
  __syncthreads();
  if (t < FOUT) {
    float a = 0.f, b = 0.f;
    #pragma unroll
    for (int w2 = 0; w2 < 4; w2++) { a += sv[w2][t]; b += sq[w2][t]; }
    atomicAdd(&ssum[t], a);
    atomicAdd(&ssq[t], b);
  }
}

// ---------------- BN apply (+optional lrelu) ----------------
template <int FOUT, bool LRELU>
__global__ void k_bn(const float* __restrict__ h, const float* __restrict__ ssum,
                     const float* __restrict__ ssq, const float* __restrict__ gamma,
                     const float* __restrict__ beta, float* __restrict__ out)
{
  int idx = blockIdx.x * 256 + threadIdx.x;
  if (idx * 4 >= NN * FOUT) return;
  float4 v = *(const float4*)(h + (size_t)idx * 4);
  float r[4] = {v.x, v.y, v.z, v.w};
  #pragma unroll
  for (int j = 0; j < 4; j++) {
    int o = (idx * 4 + j) % FOUT;
    float mu = ssum[o] * (1.f / NN);
    float var = ssq[o] * (1.f / NN) - mu * mu;
    float sc = rsqrtf(var + BN_EPS) * gamma[o];
    float y = (r[j] - mu) * sc + beta[o];
    if (LRELU) y = lrelu_f(y);
    r[j] = y;
  }
  *(float4*)(out + (size_t)idx * 4) = make_float4(r[0], r[1], r[2], r[3]);
}

extern "C" void kernel_launch(void* const* d_in, const int* in_sizes, int n_in,
                              void* d_out, int out_size, void* d_ws, size_t ws_size,
                              hipStream_t stream)
{
  const float* x0    = (const float*)d_in[0];
  const float* ea    = (const float*)d_in[1];
  const int*   ei    = (const int*)d_in[2];
  const float* W1_0  = (const float*)d_in[3];
  const float* b1_0  = (const float*)d_in[4];
  const float* W2_0  = (const float*)d_in[5];
  const float* b2_0  = (const float*)d_in[6];
  const float* root0 = (const float*)d_in[7];
  const float* bias0 = (const float*)d_in[8];
  const float* gam0  = (const float*)d_in[9];
  const float* bet0  = (const float*)d_in[10];
  const float* W1_1  = (const float*)d_in[11];
  const float* b1_1  = (const float*)d_in[12];
  const float* W2_1  = (const float*)d_in[13];
  const float* b2_1  = (const float*)d_in[14];
  const float* root1 = (const float*)d_in[15];
  const float* bias1 = (const float*)d_in[16];
  const float* gam1  = (const float*)d_in[17];
  const float* bet1  = (const float*)d_in[18];
  const int* srcI = ei;
  const int* dstI = ei + NE;

  char* ws = (char*)d_ws;
  size_t off = 0;
  auto alloc = [&](size_t bytes) { char* p = ws + off; off += (bytes + 255) & ~(size_t)255; return p; };
  // ---- zeroed region ----
  int*   cnt   = (int*)alloc(50048 * 4);
  float* ssum0 = (float*)alloc(32 * 4);
  float* ssq0  = (float*)alloc(32 * 4);
  float* ssum1 = (float*)alloc(16 * 4);
  float* ssq1  = (float*)alloc(16 * 4);
  size_t zero_bytes = off;
  // ---- rest ----
  int*   base   = (int*)alloc(50048 * 4);
  int*   cursor = (int*)alloc(50048 * 4);
  int*   aux    = (int*)alloc(64 * 4);
  int*   perm   = (int*)alloc((size_t)NE * 4);
  __hip_bfloat16* msgb = (__hip_bfloat16*)alloc((size_t)NE * 32 * 2);  // reused for layer1 (16)
  float* h0 = (float*)alloc((size_t)NN * 32 * 4);
  float* h1 = (float*)alloc((size_t)NN * 16 * 4);
  float* x1 = (float*)alloc((size_t)NN * 32 * 4);
  __hip_bfloat16* W2T0 = (__hip_bfloat16*)alloc(512 * 512 * 2);
  __hip_bfloat16* W2T1 = (__hip_bfloat16*)alloc(512 * 512 * 2);
  __hip_bfloat16* W1T0 = (__hip_bfloat16*)alloc(512 * 8 * 2);
  __hip_bfloat16* W1T1 = (__hip_bfloat16*)alloc(512 * 8 * 2);

  hipMemsetAsync(d_ws, 0, zero_bytes, stream);

  // weight prep (merged across layers)
  k_transpose_w2<<<dim3(256, 2), 256, 0, stream>>>(W2_0, W2_1, W2T0, W2T1);
  k_transpose_w1<<<dim3(16, 2), 256, 0, stream>>>(W1_0, W1_1, W1T0, W1T1);

  // counting sort by dst (shared by both layers)
  constexpr int NSB = (NN + SCAN_ELEMS - 1) / SCAN_ELEMS;  // 49
  k_count<<<(NE + 255) / 256, 256, 0, stream>>>(dstI, cnt);
  k_scan1<<<NSB, 256, 0, stream>>>(cnt, base, aux, NN);
  k_scan2<<<1, 64, 0, stream>>>(aux, NSB);
  k_scan3<<<(NN + 255) / 256, 256, 0, stream>>>(base, cursor, aux, NN);
  k_place<<<(NE + 255) / 256, 256, 0, stream>>>(dstI, cursor, perm);

  constexpr int TM = 256;
  // layer 0
  k_edge<16, 32><<<(NE + TM - 1) / TM, 256, 0, stream>>>(x0, ea, srcI, W1T0, b1_0, W2T0, b2_0, msgb);
  k_node_agg<16, 32><<<(NN + 7) / 8, 256, 0, stream>>>(msgb, perm, base, x0, root0, bias0, h0);
  k_stats<32><<<128, 256, 0, stream>>>(h0, ssum0, ssq0);
  k_bn<32, true><<<((NN * 32 / 4) + 255) / 256, 256, 0, stream>>>(h0, ssum0, ssq0, gam0, bet0, x1);

  // layer 1
  k_edge<32, 16><<<(NE + TM - 1) / TM, 256, 0, stream>>>(x1, ea, srcI, W1T1, b1_1, W2T1, b2_1, msgb);
  k_node_agg<32, 16><<<(NN + 15) / 16, 256, 0, stream>>>(msgb, perm, base, x1, root1, bias1, h1);
  k_stats<16><<<128, 256, 0, stream>>>(h1, ssum1, ssq1);
  k_bn<16, false><<<((NN * 16 / 4) + 255) / 256, 256, 0, stream>>>(h1, ssum1, ssq1, gam1, bet1, (float*)d_out);
}